// Round 2
// baseline (1143.795 us; speedup 1.0000x reference)
//
#include <hip/hip_runtime.h>

typedef _Float16 half8 __attribute__((ext_vector_type(8)));
typedef float floatx4 __attribute__((ext_vector_type(4)));

// LDS column-group swizzle (8-elem granularity) so 16-lane fragment reads spread banks.
#define SWZ(r) ((((r) & 7) << 1) | (((r) >> 3) & 1))

__device__ __forceinline__ void gld16(const void* g, void* l) {
  __builtin_amdgcn_global_load_lds(
      (const __attribute__((address_space(1))) unsigned int*)g,
      (__attribute__((address_space(3))) unsigned int*)l, 16, 0, 0);
}

// ---------------- fp32 -> f16 convert (8 elems/thread) ----------------
__global__ void f2h(const float* __restrict__ s, _Float16* __restrict__ d, int n8) {
  int i = blockIdx.x * 256 + threadIdx.x;
  if (i >= n8) return;
  float4 a = ((const float4*)s)[2 * i];
  float4 b = ((const float4*)s)[2 * i + 1];
  half8 h;
  h[0] = (_Float16)a.x; h[1] = (_Float16)a.y; h[2] = (_Float16)a.z; h[3] = (_Float16)a.w;
  h[4] = (_Float16)b.x; h[5] = (_Float16)b.y; h[6] = (_Float16)b.z; h[7] = (_Float16)b.w;
  ((half8*)d)[i] = h;
}

__global__ void bias_concat(const float* __restrict__ bq, const float* __restrict__ bk,
                            const float* __restrict__ bv, float* __restrict__ dst) {
  int i = blockIdx.x * 256 + threadIdx.x;
  if (i < 4096) dst[i] = bq[i];
  else if (i < 5120) dst[i] = bk[i - 4096];
  else if (i < 6144) dst[i] = bv[i - 5120];
}

// ---------------- GEMM: C[m,n] = sum_k A[m,k]*B[n,k] (+bias[n]) ----------------
// A:[M][K] f16, B:[N][K] f16 row-major. 128x128 tile, BK=32, 4 waves 2x2, 16x16x32 MFMA.
template <typename OutT, bool HasBias>
__global__ __launch_bounds__(256) void gemm_bt(const _Float16* __restrict__ A,
                                               const _Float16* __restrict__ B,
                                               const float* __restrict__ bias,
                                               OutT* __restrict__ C, int M, int N, int K) {
  __shared__ _Float16 as[128 * 32];
  __shared__ _Float16 bs[128 * 32];
  const int tid = threadIdx.x;
  const int w = tid >> 6, lane = tid & 63;
  const int quad = lane >> 4, l16 = lane & 15;
  const int M0 = blockIdx.y * 128, N0 = blockIdx.x * 128;
  const int wm = (w >> 1) * 64, wn = (w & 1) * 64;

  floatx4 acc[4][4];
#pragma unroll
  for (int i = 0; i < 4; ++i)
#pragma unroll
    for (int j = 0; j < 4; ++j) acc[i][j] = (floatx4){0.f, 0.f, 0.f, 0.f};

  // staging: call c covers rows [c*64, c*64+64); thread -> (row, 8-col group)
  const int r0 = tid >> 2, g0 = tid & 3;
  const int r1 = r0 + 64;
  const int c0 = (g0 ^ ((r0 >> 1) & 3)) * 8;  // swizzled global col offset
  const int c1 = (g0 ^ ((r1 >> 1) & 3)) * 8;
  const _Float16* A0 = A + (size_t)(M0 + r0) * K + c0;
  const _Float16* A1 = A + (size_t)(M0 + r1) * K + c1;
  const _Float16* B0 = B + (size_t)(N0 + r0) * K + c0;
  const _Float16* B1 = B + (size_t)(N0 + r1) * K + c1;
  _Float16* asw = &as[w * 512];
  _Float16* bsw = &bs[w * 512];

  int aoff[4], boff[4];
#pragma unroll
  for (int mi = 0; mi < 4; ++mi) {
    int ra = wm + mi * 16 + l16;
    aoff[mi] = ra * 32 + ((quad ^ ((ra >> 1) & 3)) * 8);
    int rb = wn + mi * 16 + l16;
    boff[mi] = rb * 32 + ((quad ^ ((rb >> 1) & 3)) * 8);
  }

  for (int kk = 0; kk < K; kk += 32) {
    __syncthreads();
    gld16(A0 + kk, asw);
    gld16(A1 + kk, asw + 2048);
    gld16(B0 + kk, bsw);
    gld16(B1 + kk, bsw + 2048);
    __syncthreads();
    half8 af[4], bf[4];
#pragma unroll
    for (int i = 0; i < 4; ++i) af[i] = *(const half8*)&as[aoff[i]];
#pragma unroll
    for (int i = 0; i < 4; ++i) bf[i] = *(const half8*)&bs[boff[i]];
#pragma unroll
    for (int mi = 0; mi < 4; ++mi)
#pragma unroll
      for (int ni = 0; ni < 4; ++ni)
        acc[mi][ni] = __builtin_amdgcn_mfma_f32_16x16x32_f16(af[mi], bf[ni], acc[mi][ni], 0, 0, 0);
  }

#pragma unroll
  for (int mi = 0; mi < 4; ++mi)
#pragma unroll
    for (int ni = 0; ni < 4; ++ni) {
      int row = M0 + wm + mi * 16 + quad * 4;
      int col = N0 + wn + ni * 16 + l16;
      float bvv = HasBias ? bias[col] : 0.f;
#pragma unroll
      for (int r = 0; r < 4; ++r) {
        float v = acc[mi][ni][r] + bvv;
        C[(size_t)(row + r) * N + col] = (OutT)v;
      }
    }
}

// ---------------- RoPE for Q (scaled by 1/sqrt(HD)) and K ----------------
// qkv: [4096][6144] f16.  q_r: [B][32][2048][128], k_r: [B][8][2048][128]
__global__ void rope_qk(const _Float16* __restrict__ qkv, const float* __restrict__ cosb,
                        const float* __restrict__ sinb, _Float16* __restrict__ q_r,
                        _Float16* __restrict__ k_r) {
  int t = blockIdx.x * 256 + threadIdx.x;  // [0, 2*2048*40*64)
  int d = t & 63;
  int r = t >> 6;
  int hh = r % 40;
  int r2 = r / 40;
  int s = r2 & 2047;
  int b = r2 >> 11;
  size_t mrow = (size_t)(b * 2048 + s) * 6144;
  float c = cosb[s * 128 + d], sn = sinb[s * 128 + d];
  if (hh < 32) {
    size_t base = mrow + hh * 128 + d;
    float x1 = (float)qkv[base], x2 = (float)qkv[base + 64];
    const float sc = 0.08838834764831845f;  // 1/sqrt(128)
    float o1 = (x1 * c - x2 * sn) * sc;
    float o2 = (x2 * c + x1 * sn) * sc;
    size_t ob = ((size_t)((b * 32 + hh) * 2048 + s)) * 128 + d;
    q_r[ob] = (_Float16)o1;
    q_r[ob + 64] = (_Float16)o2;
  } else {
    int hk = hh - 32;
    size_t base = mrow + 4096 + hk * 128 + d;
    float x1 = (float)qkv[base], x2 = (float)qkv[base + 64];
    float o1 = x1 * c - x2 * sn;
    float o2 = x2 * c + x1 * sn;
    size_t ob = ((size_t)((b * 8 + hk) * 2048 + s)) * 128 + d;
    k_r[ob] = (_Float16)o1;
    k_r[ob + 64] = (_Float16)o2;
  }
}

// ---------------- V transpose: qkv v-part -> v_t[b][hv][d][s] ----------------
__global__ void v_transpose(const _Float16* __restrict__ qkv, _Float16* __restrict__ v_t) {
  __shared__ _Float16 tile[32][33];
  int st = blockIdx.x * 32, dt = blockIdx.y * 32, bh = blockIdx.z;
  int tx = threadIdx.x & 31, ty = threadIdx.x >> 5;  // ty 0..7
  int b = bh >> 3, hv = bh & 7;
#pragma unroll
  for (int j = 0; j < 4; ++j) {
    int s = st + ty + j * 8;
    tile[ty + j * 8][tx] = qkv[(size_t)(b * 2048 + s) * 6144 + 5120 + hv * 128 + dt + tx];
  }
  __syncthreads();
#pragma unroll
  for (int j = 0; j < 4; ++j)
    v_t[((size_t)bh * 128 + dt + ty + j * 8) * 2048 + st + tx] = tile[tx][ty + j * 8];
}

// ---------------- Flash attention ----------------
// q_r:[B][32][2048][128] (pre-scaled), k_r:[B][8][2048][128], v_t:[B][8][128][2048]
// att:[B*2048][4096] f16 (b,s, h*128+d)
__global__ __launch_bounds__(256, 2) void attn_kernel(const _Float16* __restrict__ q_r,
                                                      const _Float16* __restrict__ k_r,
                                                      const _Float16* __restrict__ v_t,
                                                      _Float16* __restrict__ att) {
  __shared__ _Float16 kt[128 * 128];  // K tile [kv][d]; later overlaid with P [qrow][kv]
  __shared__ _Float16 vt[128 * 128];  // V tile [d][kv]
  const int tid = threadIdx.x;
  const int w = tid >> 6, lane = tid & 63;
  const int quad = lane >> 4, l16 = lane & 15;
  const int qt = 15 - blockIdx.x;  // heavy tiles dispatch first
  const int h = blockIdx.y, b = blockIdx.z;
  const _Float16* qh = q_r + ((size_t)(b * 32 + h) * 2048) * 128;
  const _Float16* kh = k_r + ((size_t)(b * 8 + (h >> 2)) * 2048) * 128;
  const _Float16* vh = v_t + ((size_t)(b * 8 + (h >> 2)) * 128) * 2048;

  // Q fragments in registers (A-operand layout), rows qt*128 + w*32 + mi*16 + l16
  half8 aq[2][4];
#pragma unroll
  for (int mi = 0; mi < 2; ++mi)
#pragma unroll
    for (int kd = 0; kd < 4; ++kd)
      aq[mi][kd] =
          *(const half8*)&qh[(size_t)(qt * 128 + w * 32 + mi * 16 + l16) * 128 + kd * 32 + quad * 8];

  floatx4 oacc[2][8];
#pragma unroll
  for (int mi = 0; mi < 2; ++mi)
#pragma unroll
    for (int nd = 0; nd < 8; ++nd) oacc[mi][nd] = (floatx4){0.f, 0.f, 0.f, 0.f};
  float mrun[2][4], lrun[2][4];
#pragma unroll
  for (int mi = 0; mi < 2; ++mi)
#pragma unroll
    for (int r = 0; r < 4; ++r) { mrun[mi][r] = -1e30f; lrun[mi][r] = 0.f; }

  const int srow0 = tid >> 4, sgrp = tid & 15;

  for (int kti = 0; kti <= qt; ++kti) {
    __syncthreads();
    const _Float16* kg = kh + (size_t)kti * 128 * 128;
#pragma unroll
    for (int c = 0; c < 8; ++c) {
      int row = srow0 + c * 16;
      int gc = (sgrp ^ SWZ(row)) * 8;
      gld16(kg + row * 128 + gc, &kt[w * 512 + c * 2048]);
    }
#pragma unroll
    for (int c = 0; c < 8; ++c) {
      int row = srow0 + c * 16;
      int gc = (sgrp ^ SWZ(row)) * 8;
      gld16(vh + (size_t)row * 2048 + kti * 128 + gc, &vt[w * 512 + c * 2048]);
    }
    __syncthreads();

    // S = Q K^T
    floatx4 sacc[2][8];
#pragma unroll
    for (int mi = 0; mi < 2; ++mi)
#pragma unroll
      for (int ni = 0; ni < 8; ++ni) sacc[mi][ni] = (floatx4){0.f, 0.f, 0.f, 0.f};
#pragma unroll
    for (int ni = 0; ni < 8; ++ni) {
      int row = ni * 16 + l16;
#pragma unroll
      for (int kd = 0; kd < 4; ++kd) {
        int grp = (kd * 4 + quad) ^ SWZ(row);
        half8 bk = *(const half8*)&kt[row * 128 + grp * 8];
        sacc[0][ni] = __builtin_amdgcn_mfma_f32_16x16x32_f16(aq[0][kd], bk, sacc[0][ni], 0, 0, 0);
        sacc[1][ni] = __builtin_amdgcn_mfma_f32_16x16x32_f16(aq[1][kd], bk, sacc[1][ni], 0, 0, 0);
      }
    }

    if (kti == qt) {  // causal mask on diagonal tile
#pragma unroll
      for (int mi = 0; mi < 2; ++mi)
#pragma unroll
        for (int ni = 0; ni < 8; ++ni)
#pragma unroll
          for (int r = 0; r < 4; ++r)
            if (ni * 16 + l16 > w * 32 + mi * 16 + quad * 4 + r) sacc[mi][ni][r] = -1e30f;
    }

    // online softmax per q-row
#pragma unroll
    for (int mi = 0; mi < 2; ++mi)
#pragma unroll
      for (int r = 0; r < 4; ++r) {
        float tm = sacc[mi][0][r];
#pragma unroll
        for (int ni = 1; ni < 8; ++ni) tm = fmaxf(tm, sacc[mi][ni][r]);
#pragma unroll
        for (int o = 1; o < 16; o <<= 1) tm = fmaxf(tm, __shfl_xor(tm, o, 64));
        float nm = fmaxf(mrun[mi][r], tm);
        float al = __expf(mrun[mi][r] - nm);
        mrun[mi][r] = nm;
        float ts = 0.f;
#pragma unroll
        for (int ni = 0; ni < 8; ++ni) {
          float p = __expf(sacc[mi][ni][r] - nm);
          sacc[mi][ni][r] = p;
          ts += p;
        }
#pragma unroll
        for (int o = 1; o < 16; o <<= 1) ts += __shfl_xor(ts, o, 64);
        lrun[mi][r] = lrun[mi][r] * al + ts;
        // BUGFIX (R1): scale ONLY row r of the 4-row accumulator. Previously
        // `oacc[mi][nd] *= al` scaled all 4 rows by row r's alpha -> each row
        // ended up scaled by the product of all four alphas (absmax 1.1).
#pragma unroll
        for (int nd = 0; nd < 8; ++nd) oacc[mi][nd][r] *= al;
      }

    __syncthreads();  // all waves done reading K before P overlays it
#pragma unroll
    for (int mi = 0; mi < 2; ++mi)
#pragma unroll
      for (int ni = 0; ni < 8; ++ni)
#pragma unroll
        for (int r = 0; r < 4; ++r) {
          int row = w * 32 + mi * 16 + quad * 4 + r;
          int col = ni * 16 + l16;
          int gs = (col >> 3) ^ SWZ(row);
          kt[row * 128 + gs * 8 + (col & 7)] = (_Float16)sacc[mi][ni][r];
        }

    // O += P V   (wave reads only its own P rows: no barrier needed)
#pragma unroll
    for (int ks = 0; ks < 4; ++ks) {
      half8 pa[2];
#pragma unroll
      for (int mi = 0; mi < 2; ++mi) {
        int row = w * 32 + mi * 16 + l16;
        int grp = (ks * 4 + quad) ^ SWZ(row);
        pa[mi] = *(const half8*)&kt[row * 128 + grp * 8];
      }
#pragma unroll
      for (int nd = 0; nd < 8; ++nd) {
        int rowv = nd * 16 + l16;
        int grpv = (ks * 4 + quad) ^ SWZ(rowv);
        half8 vb = *(const half8*)&vt[rowv * 128 + grpv * 8];
        oacc[0][nd] = __builtin_amdgcn_mfma_f32_16x16x32_f16(pa[0], vb, oacc[0][nd], 0, 0, 0);
        oacc[1][nd] = __builtin_amdgcn_mfma_f32_16x16x32_f16(pa[1], vb, oacc[1][nd], 0, 0, 0);
      }
    }
  }

#pragma unroll
  for (int mi = 0; mi < 2; ++mi)
#pragma unroll
    for (int r = 0; r < 4; ++r) {
      float inv = 1.f / lrun[mi][r];
      int srow = qt * 128 + w * 32 + mi * 16 + quad * 4 + r;
#pragma unroll
      for (int nd = 0; nd < 8; ++nd) {
        int col = h * 128 + nd * 16 + l16;
        att[((size_t)b * 2048 + srow) * 4096 + col] = (_Float16)(oacc[mi][nd][r] * inv);
      }
    }
}

extern "C" void kernel_launch(void* const* d_in, const int* in_sizes, int n_in, void* d_out,
                              int out_size, void* d_ws, size_t ws_size, hipStream_t stream) {
  const float* x = (const float*)d_in[0];
  const float* cosb = (const float*)d_in[1];
  const float* sinb = (const float*)d_in[2];
  const float* Wq = (const float*)d_in[3];
  const float* bq = (const float*)d_in[4];
  const float* Wk = (const float*)d_in[5];
  const float* bk = (const float*)d_in[6];
  const float* Wv = (const float*)d_in[7];
  const float* bv = (const float*)d_in[8];
  const float* Wo = (const float*)d_in[9];
  float* out = (float*)d_out;

  char* p = (char*)d_ws;
  _Float16* xb = (_Float16*)p;   p += (size_t)4096 * 4096 * 2;
  _Float16* wqkv = (_Float16*)p; p += (size_t)6144 * 4096 * 2;
  _Float16* wo_b = (_Float16*)p; p += (size_t)4096 * 4096 * 2;
  _Float16* qkv = (_Float16*)p;  p += (size_t)4096 * 6144 * 2;
  _Float16* q_r = (_Float16*)p;  p += (size_t)2 * 32 * 2048 * 128 * 2;
  _Float16* k_r = (_Float16*)p;  p += (size_t)2 * 8 * 2048 * 128 * 2;
  _Float16* v_t = (_Float16*)p;  p += (size_t)2 * 8 * 128 * 2048 * 2;
  _Float16* att = (_Float16*)p;  p += (size_t)4096 * 4096 * 2;
  float* biasc = (float*)p;      p += 6144 * 4;

  f2h<<<8192, 256, 0, stream>>>(x, xb, 2097152);
  f2h<<<8192, 256, 0, stream>>>(Wq, wqkv, 2097152);
  f2h<<<2048, 256, 0, stream>>>(Wk, wqkv + (size_t)4096 * 4096, 524288);
  f2h<<<2048, 256, 0, stream>>>(Wv, wqkv + (size_t)5120 * 4096, 524288);
  f2h<<<8192, 256, 0, stream>>>(Wo, wo_b, 2097152);
  bias_concat<<<24, 256, 0, stream>>>(bq, bk, bv, biasc);

  gemm_bt<_Float16, true><<<dim3(48, 32), 256, 0, stream>>>(xb, wqkv, biasc, qkv, 4096, 6144, 4096);
  rope_qk<<<40960, 256, 0, stream>>>(qkv, cosb, sinb, q_r, k_r);
  v_transpose<<<dim3(64, 4, 16), 256, 0, stream>>>(qkv, v_t);
  attn_kernel<<<dim3(16, 32, 2), 256, 0, stream>>>(q_r, k_r, v_t, att);
  gemm_bt<float, false><<<dim3(32, 32), 256, 0, stream>>>(att, wo_b, nullptr, out, 4096, 4096, 4096);
}